// Round 14
// baseline (481.757 us; speedup 1.0000x reference)
//
#include <hip/hip_runtime.h>
#include <hip/hip_bf16.h>
#include <cstddef>

// ---------------------------------------------------------------------------
// 3-layer GAT (PyG-style) on MI355X.
// Round 14: (1) h8 aggregate - each lane loads f16x8 (16B), wave processes
// 2 edges per load instruction (1KB/instr), halving VMEM+exp issues; per-head
// max via m_lds broadcast, halves combined by shfl_xor(32).
// (2) bufB stored fp16 (identity: L2 gemm casts A to fp16 anyway) -> halves
// L1-agg writes + L2-gemm A fetch. bufC stays fp32 (L3 math is fp32).
// GEMM: MFMA v_mfma_f32_16x16x32_f16, fp32 accum (r13, measured good).
// ---------------------------------------------------------------------------

typedef _Float16 h4 __attribute__((ext_vector_type(4)));
typedef _Float16 f16x4 __attribute__((ext_vector_type(4)));
typedef _Float16 f16x8 __attribute__((ext_vector_type(8)));
typedef float f32x4 __attribute__((ext_vector_type(4)));

#define ECAP 96  // LDS-cached logits per node; deg>ECAP falls back to re-gather
#define LSTR 40  // LDS K-stride in f16 (32 data + 8 pad -> bank spread)

// ---------------- CSR build ----------------

__global__ void zero_i32(int* __restrict__ p, int n) {
  int i = blockIdx.x * 256 + threadIdx.x;
  if (i < n) p[i] = 0;
}

__global__ void edge_histogram(const int* __restrict__ ei, int E, int nnodes,
                               int* __restrict__ counts) {
  int e = blockIdx.x * 256 + threadIdx.x;
  int tot = E + nnodes;
  if (e >= tot) return;
  int dst = (e < E) ? ei[E + e] : (e - E);
  atomicAdd(&counts[dst], 1);
}

__global__ void scan_block(const int* __restrict__ in, int* __restrict__ out,
                           int* __restrict__ sums, int n) {
  __shared__ int tmp[256];
  int i = blockIdx.x * 256 + threadIdx.x;
  int v = (i < n) ? in[i] : 0;
  tmp[threadIdx.x] = v;
  __syncthreads();
  for (int off = 1; off < 256; off <<= 1) {
    int t = (threadIdx.x >= off) ? tmp[threadIdx.x - off] : 0;
    __syncthreads();
    tmp[threadIdx.x] += t;
    __syncthreads();
  }
  if (i < n) out[i] = tmp[threadIdx.x] - v;  // exclusive
  if (sums && threadIdx.x == 255) sums[blockIdx.x] = tmp[255];
}

__global__ void add_offsets(int* __restrict__ row_ptr, const int* __restrict__ offs,
                            int* __restrict__ nextp, int n, int total) {
  int i = blockIdx.x * 256 + threadIdx.x;
  if (i < n) {
    int v = row_ptr[i] + offs[blockIdx.x];
    row_ptr[i] = v;
    nextp[i] = v;
  }
  if (i == 0) row_ptr[n] = total;
}

__global__ void edge_scatter(const int* __restrict__ ei, int E, int nnodes,
                             int* __restrict__ nextp, int* __restrict__ col_idx) {
  int e = blockIdx.x * 256 + threadIdx.x;
  int tot = E + nnodes;
  if (e >= tot) return;
  int src = (e < E) ? ei[e] : (e - E);
  int dst = (e < E) ? ei[E + e] : (e - E);
  int pos = atomicAdd(&nextp[dst], 1);
  col_idx[pos] = src;
}

// ---------------- fused MFMA GEMM + al: h16 = A@B, al_s/al_d ---------------
// N fixed 256. BM=128, BN=128 (2 heads), KB=32, 256 threads = 4 waves (2x2),
// each wave owns a 64x64 output = 4x4 tiles of 16x16x32 MFMA.
// AT = float (layer 1, x input) or _Float16 (layer 2, bufB16).

template <typename AT>
__global__ __launch_bounds__(256) void gemm_al(
    const AT* __restrict__ A, const float* __restrict__ B,
    _Float16* __restrict__ C16, const float* __restrict__ a_src,
    const float* __restrict__ a_dst, float* __restrict__ alS,
    float* __restrict__ alD, int M, int K) {
  __shared__ _Float16 As16[128][LSTR];
  __shared__ _Float16 Bs16[128][LSTR];
  int t = threadIdx.x;
  int m0 = blockIdx.x * 128;
  int by = blockIdx.y;
  int n0 = by * 128;

  int l = t & 63;
  int w = t >> 6;
  int wr = w >> 1, wc = w & 1;
  int lr = l & 15;          // row (A) / col (B) within 16-tile
  int lk = (l >> 4) * 8;    // k base within 32

  // B staging decomposition: thread -> (col, k-half)
  int colB = t & 127;
  int kqB = t >> 7;  // 0..1, covers k = kqB*16 .. +15

  f32x4 acc[4][4];
#pragma unroll
  for (int i = 0; i < 4; ++i)
#pragma unroll
    for (int j = 0; j < 4; ++j) acc[i][j] = (f32x4){0.f, 0.f, 0.f, 0.f};

  const float4 f40 = {0.f, 0.f, 0.f, 0.f};
  for (int k0 = 0; k0 < K; k0 += 32) {
    // A tile: 128 rows x 32 k -> fp16, row-major K-contig
    if constexpr (sizeof(AT) == 4) {
#pragma unroll
      for (int r = 0; r < 4; ++r) {
        int idx = t + r * 256;   // 0..1023
        int row = idx >> 3;      // 0..127
        int q = idx & 7;         // k quad
        int gr = m0 + row;
        float4 v = (gr < M) ? *(const float4*)&A[(size_t)gr * K + k0 + q * 4]
                            : f40;
        f16x4 hv = {(_Float16)v.x, (_Float16)v.y, (_Float16)v.z,
                    (_Float16)v.w};
        *(f16x4*)&As16[row][q * 4] = hv;
      }
    } else {
#pragma unroll
      for (int r = 0; r < 2; ++r) {
        int idx = t + r * 256;   // 0..511
        int row = idx >> 2;      // 0..127
        int q = idx & 3;         // k octet
        int gr = m0 + row;
        f16x8 hv = (f16x8){0, 0, 0, 0, 0, 0, 0, 0};
        if (gr < M)
          hv = *(const f16x8*)&A[(size_t)gr * K + k0 + q * 8];
        *(f16x8*)&As16[row][q * 8] = hv;
      }
    }
    // B tile: 32 k x 128 cols, transposed into Bs16[col][k], fp32 -> fp16
#pragma unroll
    for (int half = 0; half < 2; ++half) {
      f16x8 hv;
#pragma unroll
      for (int j = 0; j < 8; ++j) {
        int k = kqB * 16 + half * 8 + j;
        hv[j] = (_Float16)B[(size_t)(k0 + k) * 256 + n0 + colB];
      }
      *(f16x8*)&Bs16[colB][kqB * 16 + half * 8] = hv;
    }
    __syncthreads();
    // fragments + MFMA: a-frags held, b-frags streamed (VGPR liveness)
    f16x8 af0 = *(const f16x8*)&As16[wr * 64 + 0 * 16 + lr][lk];
    f16x8 af1 = *(const f16x8*)&As16[wr * 64 + 1 * 16 + lr][lk];
    f16x8 af2 = *(const f16x8*)&As16[wr * 64 + 2 * 16 + lr][lk];
    f16x8 af3 = *(const f16x8*)&As16[wr * 64 + 3 * 16 + lr][lk];
#pragma unroll
    for (int j = 0; j < 4; ++j) {
      f16x8 bf = *(const f16x8*)&Bs16[wc * 64 + j * 16 + lr][lk];
      acc[0][j] = __builtin_amdgcn_mfma_f32_16x16x32_f16(af0, bf, acc[0][j], 0, 0, 0);
      acc[1][j] = __builtin_amdgcn_mfma_f32_16x16x32_f16(af1, bf, acc[1][j], 0, 0, 0);
      acc[2][j] = __builtin_amdgcn_mfma_f32_16x16x32_f16(af2, bf, acc[2][j], 0, 0, 0);
      acc[3][j] = __builtin_amdgcn_mfma_f32_16x16x32_f16(af3, bf, acc[3][j], 0, 0, 0);
    }
    __syncthreads();
  }

  // ---- epilogue: h16 store + fused al (head = by*2 + wc) ----
  int head = by * 2 + wc;
  float as4[4], ad4[4];
#pragma unroll
  for (int j = 0; j < 4; ++j) {
    as4[j] = a_src[head * 64 + j * 16 + lr];
    ad4[j] = a_dst[head * 64 + j * 16 + lr];
  }
#pragma unroll
  for (int i = 0; i < 4; ++i) {
#pragma unroll
    for (int reg = 0; reg < 4; ++reg) {
      int gr = m0 + wr * 64 + i * 16 + (l >> 4) * 4 + reg;
      float ps = acc[i][0][reg] * as4[0] + acc[i][1][reg] * as4[1] +
                 acc[i][2][reg] * as4[2] + acc[i][3][reg] * as4[3];
      float pd = acc[i][0][reg] * ad4[0] + acc[i][1][reg] * ad4[1] +
                 acc[i][2][reg] * ad4[2] + acc[i][3][reg] * ad4[3];
#pragma unroll
      for (int off = 1; off < 16; off <<= 1) {
        ps += __shfl_xor(ps, off);
        pd += __shfl_xor(pd, off);
      }
      if (gr < M) {
#pragma unroll
        for (int j = 0; j < 4; ++j)
          C16[(size_t)gr * 256 + n0 + wc * 64 + j * 16 + lr] =
              (_Float16)acc[i][j][reg];
        if (lr == 0) {
          alS[gr * 4 + head] = ps;
          alD[gr * 4 + head] = pd;
        }
      }
    }
  }
}

// ---------------- per-dst two-pass softmax aggregation (heads=4, C=64) ------
// Pass 1: 16 edges x 4 heads parallel -> e_lds + per-head max (m_lds).
// Pass 2: lane owns 8 channels (f16x8 gather, 16B); wave processes 2 edges
// per load instruction (half = l>>5); halves merged via shfl_xor(32).
// OT: _Float16 (layer-1 out, feeds fp16 GEMM: numerically identity) or float.

template <bool RELU, typename OT>
__global__ __launch_bounds__(256) void gat_aggregate(
    const _Float16* __restrict__ h, const float* __restrict__ al_s,
    const float* __restrict__ al_d, const int* __restrict__ row_ptr,
    const int* __restrict__ col_idx, const float* __restrict__ bias,
    OT* __restrict__ out, int nnodes) {
  __shared__ float e_lds[4][ECAP * 4];
  __shared__ float m_lds[4][4];
  int wv = threadIdx.x >> 6;
  int n = blockIdx.x * 4 + wv;
  if (n >= nnodes) return;  // never taken: N % 4 == 0 (50000)
  int l = threadIdx.x & 63;
  int hd = l >> 4;
  int sub = l & 15;
  int beg = row_ptr[n], end = row_ptr[n + 1];
  int deg = end - beg;
  float ad = al_d[n * 4 + hd];

  // ---- pass 1: logits + per-head max ----
  float m = -3.0e38f;
  for (int j0 = 0; j0 < deg; j0 += 16) {
    int j = j0 + sub;
    float e = -3.0e38f;
    if (j < deg) {
      int src = col_idx[beg + j];
      e = al_s[src * 4 + hd] + ad;
      e = fmaxf(e, 0.2f * e);  // leaky_relu(0.2)
      if (j < ECAP) e_lds[wv][j * 4 + hd] = e;
    }
    m = fmaxf(m, e);
  }
#pragma unroll
  for (int off = 1; off < 16; off <<= 1) m = fmaxf(m, __shfl_xor(m, off));
  if (sub == 0) m_lds[wv][hd] = m;
  __syncthreads();

  // ---- pass 2: 2 edges per iteration, 8 channels per lane ----
  int half = l >> 5;        // which edge of each pair
  int lr = l & 31;          // channel group: channels lr*8 .. lr*8+7
  int hh = lr >> 3;         // head of these channels
  float mh = m_lds[wv][hh];
  float adh = al_d[n * 4 + hh];  // for deg>ECAP recompute
  float s = 0.f;
  float acc[8];
#pragma unroll
  for (int q = 0; q < 8; ++q) acc[q] = 0.f;

  int jcap = deg < ECAP ? deg : ECAP;
  int j = 0;
  // main loop: 8 edges (4 pairs) per iteration, all logits in LDS
  for (; j + 8 <= jcap; j += 8) {
    int e0 = j + 0 + half, e1 = j + 2 + half, e2 = j + 4 + half,
        e3 = j + 6 + half;
    int s0 = col_idx[beg + e0];
    int s1 = col_idx[beg + e1];
    int s2 = col_idx[beg + e2];
    int s3 = col_idx[beg + e3];
    f16x8 hv0 = *(const f16x8*)&h[(size_t)s0 * 256 + lr * 8];
    f16x8 hv1 = *(const f16x8*)&h[(size_t)s1 * 256 + lr * 8];
    f16x8 hv2 = *(const f16x8*)&h[(size_t)s2 * 256 + lr * 8];
    f16x8 hv3 = *(const f16x8*)&h[(size_t)s3 * 256 + lr * 8];
    float p0 = __expf(e_lds[wv][e0 * 4 + hh] - mh);
    float p1 = __expf(e_lds[wv][e1 * 4 + hh] - mh);
    float p2 = __expf(e_lds[wv][e2 * 4 + hh] - mh);
    float p3 = __expf(e_lds[wv][e3 * 4 + hh] - mh);
    s += (p0 + p1) + (p2 + p3);
#pragma unroll
    for (int q = 0; q < 8; ++q)
      acc[q] += p0 * (float)hv0[q] + p1 * (float)hv1[q] +
                p2 * (float)hv2[q] + p3 * (float)hv3[q];
  }
  // tail: 2 edges per iteration, per-edge bounds/ECAP handling
  for (; j < deg; j += 2) {
    int ee = j + half;
    float p = 0.f;
    f16x8 hv = (f16x8){0, 0, 0, 0, 0, 0, 0, 0};
    if (ee < deg) {
      int src = col_idx[beg + ee];
      hv = *(const f16x8*)&h[(size_t)src * 256 + lr * 8];
      float e;
      if (ee < ECAP) {
        e = e_lds[wv][ee * 4 + hh];
      } else {
        e = al_s[src * 4 + hh] + adh;
        e = fmaxf(e, 0.2f * e);
      }
      p = __expf(e - mh);
    }
    s += p;
#pragma unroll
    for (int q = 0; q < 8; ++q) acc[q] += p * (float)hv[q];
  }

  // merge the two halves (lane l <-> l^32)
  s += __shfl_xor(s, 32);
#pragma unroll
  for (int q = 0; q < 8; ++q) acc[q] += __shfl_xor(acc[q], 32);

  float inv = 1.f / (s + 1e-16f);
  int cbase = lr * 8 + half * 4;  // half0 -> low quad, half1 -> high quad
  float4 bv = *(const float4*)&bias[cbase];
  float o[4];
#pragma unroll
  for (int q = 0; q < 4; ++q) {
    float a = half ? acc[4 + q] : acc[q];  // constant indices, cndmask select
    o[q] = a * inv;
  }
  o[0] += bv.x;
  o[1] += bv.y;
  o[2] += bv.z;
  o[3] += bv.w;
  if (RELU) {
#pragma unroll
    for (int q = 0; q < 4; ++q) o[q] = fmaxf(o[q], 0.f);
  }
  if constexpr (sizeof(OT) == 2) {
    h4 ov = {(_Float16)o[0], (_Float16)o[1], (_Float16)o[2], (_Float16)o[3]};
    *(h4*)&out[(size_t)n * 256 + cbase] = ov;
  } else {
    float4 ov = {o[0], o[1], o[2], o[3]};
    *(float4*)&out[(size_t)n * 256 + cbase] = ov;
  }
}

// ---------------- layer 3: tiny GEMM (256->5) fused with al3 ----------------

__global__ __launch_bounds__(256) void gemm3_al(const float* __restrict__ Hin,
                                                const float* __restrict__ W3,
                                                const float* __restrict__ a_src3,
                                                const float* __restrict__ a_dst3,
                                                float* __restrict__ h3,
                                                float* __restrict__ al_s,
                                                float* __restrict__ al_d,
                                                int nnodes) {
  int n = blockIdx.x * 4 + (threadIdx.x >> 6);
  if (n >= nnodes) return;
  int l = threadIdx.x & 63;
  float4 hv = *(const float4*)&Hin[(size_t)n * 256 + l * 4];
  float acc[5];
#pragma unroll
  for (int cc = 0; cc < 5; ++cc) {
    acc[cc] = hv.x * W3[(l * 4 + 0) * 5 + cc] + hv.y * W3[(l * 4 + 1) * 5 + cc] +
              hv.z * W3[(l * 4 + 2) * 5 + cc] + hv.w * W3[(l * 4 + 3) * 5 + cc];
  }
#pragma unroll
  for (int cc = 0; cc < 5; ++cc)
#pragma unroll
    for (int off = 32; off; off >>= 1) acc[cc] += __shfl_xor(acc[cc], off);
  if (l == 0) {
    float as = 0.f, adv = 0.f;
#pragma unroll
    for (int cc = 0; cc < 5; ++cc) {
      h3[(size_t)n * 5 + cc] = acc[cc];
      as += acc[cc] * a_src3[cc];
      adv += acc[cc] * a_dst3[cc];
    }
    al_s[n] = as;
    al_d[n] = adv;
  }
}

// two-pass (parallel logits, no serial exp-rescale chain), heads=1, C=5

__global__ __launch_bounds__(256) void gat_aggregate3(
    const float* __restrict__ h3, const float* __restrict__ al_s,
    const float* __restrict__ al_d, const int* __restrict__ row_ptr,
    const int* __restrict__ col_idx, const float* __restrict__ b3,
    float* __restrict__ out, int nnodes) {
  __shared__ float e_lds[4][ECAP];
  int wv = threadIdx.x >> 6;
  int n = blockIdx.x * 4 + wv;
  if (n >= nnodes) return;
  int l = threadIdx.x & 63;
  int beg = row_ptr[n], end = row_ptr[n + 1];
  int deg = end - beg;
  float ad = al_d[n];

  // pass 1: all 64 lanes compute logits in parallel
  float m = -3.0e38f;
  for (int j0 = 0; j0 < deg; j0 += 64) {
    int j = j0 + l;
    float e = -3.0e38f;
    if (j < deg) {
      int src = col_idx[beg + j];
      e = al_s[src] + ad;
      e = fmaxf(e, 0.2f * e);
      if (j < ECAP) e_lds[wv][j] = e;
    }
    m = fmaxf(m, e);
  }
#pragma unroll
  for (int off = 1; off < 64; off <<= 1) m = fmaxf(m, __shfl_xor(m, off));

  // s: parallel partial sums over LDS/recomputed logits
  float sp = 0.f;
  for (int j = l; j < deg; j += 64) {
    float e;
    if (j < ECAP) {
      e = e_lds[wv][j];
    } else {
      int src = col_idx[beg + j];
      e = al_s[src] + ad;
      e = fmaxf(e, 0.2f * e);
    }
    sp += __expf(e - m);
  }
#pragma unroll
  for (int off = 1; off < 64; off <<= 1) sp += __shfl_xor(sp, off);
  float s = sp;

  // pass 2: lanes 0..4 gather h3 and accumulate (h3 is 1MB, L2-resident)
  float acc = 0.f;
  if (l < 5) {
    for (int j = 0; j < deg; ++j) {
      float e;
      if (j < ECAP) {
        e = e_lds[wv][j];
      } else {
        int src0 = col_idx[beg + j];
        e = al_s[src0] + ad;
        e = fmaxf(e, 0.2f * e);
      }
      float p = __expf(e - m);
      int src = col_idx[beg + j];
      acc += p * h3[(size_t)src * 5 + l];
    }
    out[(size_t)n * 5 + l] = acc / (s + 1e-16f) + b3[l];
  }
}

// ---------------- launch ----------------

extern "C" void kernel_launch(void* const* d_in, const int* in_sizes, int n_in,
                              void* d_out, int out_size, void* d_ws, size_t ws_size,
                              hipStream_t stream) {
  const float* x = (const float*)d_in[0];
  const int* ei = (const int*)d_in[1];
  const float* W1 = (const float*)d_in[2];
  const float* as1 = (const float*)d_in[3];
  const float* ad1 = (const float*)d_in[4];
  const float* b1 = (const float*)d_in[5];
  const float* W2 = (const float*)d_in[6];
  const float* as2 = (const float*)d_in[7];
  const float* ad2 = (const float*)d_in[8];
  const float* b2 = (const float*)d_in[9];
  const float* W3 = (const float*)d_in[10];
  const float* as3 = (const float*)d_in[11];
  const float* ad3 = (const float*)d_in[12];
  const float* b3 = (const float*)d_in[13];

  int N = in_sizes[0] / 128;  // 50000
  int E = in_sizes[1] / 2;    // 800000
  int tot = E + N;            // 850000

  char* w = (char*)d_ws;
  size_t off = 0;
  auto alloc = [&](size_t bytes) -> void* {
    void* p = w + off;
    off += (bytes + 255) & ~(size_t)255;
    return p;
  };
  _Float16* h16 = (_Float16*)alloc((size_t)N * 256 * 2);
  _Float16* bufB16 = (_Float16*)alloc((size_t)N * 256 * 2);
  float* bufC = (float*)alloc((size_t)N * 256 * 4);
  float* h3 = (float*)alloc((size_t)N * 5 * 4);
  float* alS = (float*)alloc((size_t)N * 4 * 4);
  float* alD = (float*)alloc((size_t)N * 4 * 4);
  int* row_ptr = (int*)alloc(((size_t)N + 1) * 4);
  int* nextp = (int*)alloc((size_t)N * 4);
  int* bsums = (int*)alloc(256 * 4);
  int* col_idx = (int*)alloc((size_t)tot * 4);
  (void)ws_size;

  int nbN = (N + 255) / 256;
  int nbE = (tot + 255) / 256;
  int nb4 = (N + 3) / 4;

  // CSR build (counts live in nextp)
  zero_i32<<<nbN, 256, 0, stream>>>(nextp, N);
  edge_histogram<<<nbE, 256, 0, stream>>>(ei, E, N, nextp);
  scan_block<<<nbN, 256, 0, stream>>>(nextp, row_ptr, bsums, N);
  scan_block<<<1, 256, 0, stream>>>(bsums, bsums, nullptr, nbN);
  add_offsets<<<nbN, 256, 0, stream>>>(row_ptr, bsums, nextp, N, tot);
  edge_scatter<<<nbE, 256, 0, stream>>>(ei, E, N, nextp, col_idx);

  dim3 g1((N + 127) / 128, 2);

  // layer 1 (A fp32; aggregate writes fp16 bufB — identity vs fp32+cast)
  gemm_al<float><<<g1, 256, 0, stream>>>(x, W1, h16, as1, ad1, alS, alD, N, 128);
  gat_aggregate<true, _Float16><<<nb4, 256, 0, stream>>>(
      h16, alS, alD, row_ptr, col_idx, b1, bufB16, N);
  // layer 2 (A fp16; aggregate writes fp32 bufC — layer-3 math stays fp32)
  gemm_al<_Float16><<<g1, 256, 0, stream>>>(bufB16, W2, h16, as2, ad2, alS,
                                            alD, N, 256);
  gat_aggregate<true, float><<<nb4, 256, 0, stream>>>(
      h16, alS, alD, row_ptr, col_idx, b2, bufC, N);
  // layer 3
  gemm3_al<<<nb4, 256, 0, stream>>>(bufC, W3, as3, ad3, h3, alS, alD, N);
  gat_aggregate3<<<nb4, 256, 0, stream>>>(h3, alS, alD, row_ptr, col_idx, b3,
                                          (float*)d_out, N);
}